// Round 6
// baseline (160.330 us; speedup 1.0000x reference)
//
#include <hip/hip_runtime.h>
#include <hip/hip_bf16.h>
#include <cstdint>

typedef __attribute__((ext_vector_type(8))) short short8;
typedef __attribute__((ext_vector_type(8))) unsigned short ushort8;
typedef __attribute__((ext_vector_type(4))) float f32x4;

#define B_TRIALS 256
#define F_BINS   100
#define N_UNITS  512
#define P_CH     512
#define G_SESS   10
#define H_DIM    1024  // 2N
#define TOT_ROWS (B_TRIALS * F_BINS)  // 25600
#define NT_MAX   110                  // max 256-row tiles over 10 session groups

// f32 -> bf16 round-to-nearest-even (finite inputs)
__device__ __forceinline__ unsigned short f2bf(float f) {
  unsigned int u = __builtin_bit_cast(unsigned int, f);
  u += 0x7fffu + ((u >> 16) & 1u);
  return (unsigned short)(u >> 16);
}

// async global->LDS, 16B per lane; lds dest must be wave-uniform base (+lane*16 by HW)
__device__ __forceinline__ void gload16(const void* gsrc, void* ldst) {
  __builtin_amdgcn_global_load_lds(
      (const __attribute__((address_space(1))) unsigned int*)gsrc,
      (__attribute__((address_space(3))) unsigned int*)ldst, 16, 0, 0);
}

// ---------------- planner: stable counting sort of trials by eid ----------------
__global__ void planner(const int* __restrict__ eid, int* __restrict__ rowmap,
                        int* __restrict__ tile_meta) {
  __shared__ int e[B_TRIALS], cnt[G_SESS], off[G_SESS], groff[G_SESS + 1], perm[B_TRIALS];
  int t = threadIdx.x;
  e[t] = eid[t];
  if (t < G_SESS) cnt[t] = 0;
  __syncthreads();
  atomicAdd(&cnt[e[t]], 1);
  __syncthreads();
  if (t == 0) {
    int s = 0, r = 0;
    for (int g = 0; g < G_SESS; g++) {
      off[g] = s; s += cnt[g];
      groff[g] = r; r += cnt[g] * F_BINS;
    }
    groff[G_SESS] = r;  // 25600
  }
  __syncthreads();
  int g = e[t], rank = 0;
  for (int j = 0; j < t; j++) rank += (e[j] == g);
  perm[off[g] + rank] = t;
  __syncthreads();
  for (int i = t; i < TOT_ROWS; i += 256) {
    int gg = 0;
    while (gg + 1 < G_SESS && i >= groff[gg + 1]) gg++;
    int loc = i - groff[gg];
    rowmap[i] = perm[off[gg] + loc / F_BINS] * F_BINS + loc % F_BINS;
  }
  if (t == 0) {
    int ti = 0;
    for (int g2 = 0; g2 < G_SESS; g2++) {
      int rows = cnt[g2] * F_BINS;
      int base = groff[g2];
      for (int r0 = 0; r0 < rows; r0 += 256) {
        tile_meta[ti * 3 + 0] = g2;
        tile_meta[ti * 3 + 1] = base + r0;
        tile_meta[ti * 3 + 2] = (rows - r0 < 256) ? (rows - r0) : 256;
        ti++;
      }
    }
    for (; ti < NT_MAX; ti++) {
      tile_meta[ti * 3 + 0] = -1; tile_meta[ti * 3 + 1] = 0; tile_meta[ti * 3 + 2] = 0;
    }
  }
}

// ---------------- one-time casts ----------------
__global__ void cast_x(const float* __restrict__ src,
                       unsigned short* __restrict__ dst, int n8) {
  int i = blockIdx.x * blockDim.x + threadIdx.x;
  int stride = gridDim.x * blockDim.x;
  for (; i < n8; i += stride) {
    float4 v0 = ((const float4*)src)[(size_t)i * 2];
    float4 v1 = ((const float4*)src)[(size_t)i * 2 + 1];
    ushort8 w;
    w[0] = f2bf(v0.x); w[1] = f2bf(v0.y); w[2] = f2bf(v0.z); w[3] = f2bf(v0.w);
    w[4] = f2bf(v1.x); w[5] = f2bf(v1.y); w[6] = f2bf(v1.z); w[7] = f2bf(v1.w);
    ((ushort8*)dst)[i] = w;
  }
}

// src: [g][K][N] f32 -> dst: [g][N][K] bf16
__global__ void cast_transpose(const float* __restrict__ src,
                               unsigned short* __restrict__ dst,
                               int K, int N) {
  __shared__ float tile[32][33];
  int g = blockIdx.z;
  int n0 = blockIdx.x * 32, k0 = blockIdx.y * 32;
  const float* s = src + (size_t)g * K * N;
  unsigned short* d = dst + (size_t)g * N * K;
  int t = threadIdx.x;
  int r = t >> 3, c = (t & 7) * 4;
  float4 v = *(const float4*)(s + (size_t)(k0 + r) * N + n0 + c);
  tile[r][c + 0] = v.x; tile[r][c + 1] = v.y;
  tile[r][c + 2] = v.z; tile[r][c + 3] = v.w;
  __syncthreads();
  ushort4 o;
  o.x = f2bf(tile[c + 0][r]);
  o.y = f2bf(tile[c + 1][r]);
  o.z = f2bf(tile[c + 2][r]);
  o.w = f2bf(tile[c + 3][r]);
  *(ushort4*)(d + (size_t)(n0 + r) * K + k0 + c) = o;
}

// ---------------- grouped 256x256 GEMM, BK=32, 4-buf 3-deep, template phases ----------------
// Gate ordering (R5 bug fix): vmcnt gate for tile t+1 sits BEFORE the trailing barrier of
// tile t, so the barrier publishes every wave's gate. Per tile: two phases, each
// {ds_read frags | stage 2 gload16 (t+3) | s_barrier | lgkmcnt(0)+sched_barrier |
//  setprio(1) 16 MFMA setprio(0) | [gate] s_barrier}. vmcnt never 0 mid-loop.

#define STG_A(kt) do { int _b = (kt) & 3; size_t _k = (size_t)(kt) * 32;    \
    gload16(aptr0 + _k, &Ab[_b][(size_t)(tid & 448) * 8]);                  \
    gload16(aptr1 + _k, &Ab[_b][4096 + (size_t)(tid & 448) * 8]);           \
  } while (0)
#define STG_B(kt) do { int _b = (kt) & 3; size_t _k = (size_t)(kt) * 32;    \
    gload16(bptr0 + _k, &Bb[_b][(size_t)(tid & 448) * 8]);                  \
    gload16(bptr1 + _k, &Bb[_b][4096 + (size_t)(tid & 448) * 8]);           \
  } while (0)

template<int KTOT, int NOUT, bool IS2>
__global__ __launch_bounds__(512, 2) void gemm_grouped(
    const unsigned short* __restrict__ Asrc,
    const unsigned short* __restrict__ Wt,
    const float* __restrict__ bias,
    const int* __restrict__ rowmap,
    const int* __restrict__ tile_meta,
    unsigned short* __restrict__ hout,
    float* __restrict__ out) {
  __shared__ __align__(16) unsigned short Ab[4][256 * 32];  // 64 KiB
  __shared__ __align__(16) unsigned short Bb[4][256 * 32];  // 64 KiB

  const int mt = blockIdx.x;
  const int g = tile_meta[mt * 3 + 0];
  if (g < 0) return;
  const int row0 = tile_meta[mt * 3 + 1];
  const int valid = tile_meta[mt * 3 + 2];
  const int ncol0 = blockIdx.y * 256;

  const int tid = threadIdx.x;
  const int lane = tid & 63;
  const int w = tid >> 6;
  const int wm = w >> 2, wn = w & 3;          // 2 x 4 wave grid
  const int lr = lane & 15, lq = lane >> 4;
  const int sl8 = ((lq ^ ((lr >> 1) & 3)) * 8);  // swizzled 16B slot (ushort elems)

  const unsigned short* Wg = Wt + (size_t)g * NOUT * KTOT + (size_t)ncol0 * KTOT;
  // staging sources: thread tid -> LDS row tid>>2, slot tid&3 (per half-tile of 128 rows)
  const unsigned short *aptr0, *aptr1, *bptr0, *bptr1;
  {
    int rc = tid >> 2, q = tid & 3;
    int ko = (q ^ ((rc >> 1) & 3)) * 8;  // source pre-swizzle matches read swizzle
    int rr0 = row0 + rc;        if (rr0 > TOT_ROWS - 1) rr0 = TOT_ROWS - 1;
    int rr1 = row0 + 128 + rc;  if (rr1 > TOT_ROWS - 1) rr1 = TOT_ROWS - 1;
    int sr0 = IS2 ? rr0 : rowmap[rr0];
    int sr1 = IS2 ? rr1 : rowmap[rr1];
    aptr0 = Asrc + (size_t)sr0 * KTOT + ko;
    aptr1 = Asrc + (size_t)sr1 * KTOT + ko;
    bptr0 = Wg + (size_t)rc * KTOT + ko;
    bptr1 = Wg + (size_t)(128 + rc) * KTOT + ko;
  }

  f32x4 acc[8][4];
#pragma unroll
  for (int m = 0; m < 8; m++)
#pragma unroll
    for (int n = 0; n < 4; n++) acc[m][n] = (f32x4){0.f, 0.f, 0.f, 0.f};

  constexpr int NK = KTOT / 32;

  // prologue: stage K-tiles 0,1,2 (12 loads/wave in flight), gate tile 0, publish
  STG_A(0); STG_B(0); STG_A(1); STG_B(1); STG_A(2); STG_B(2);
  asm volatile("s_waitcnt vmcnt(8)" ::: "memory");
  __builtin_amdgcn_s_barrier();

#pragma unroll 4
  for (int t = 0; t < NK; ++t) {
    const unsigned short* Ap = &Ab[t & 3][0];
    const unsigned short* Bp = &Bb[t & 3][0];

    // ======== phase 0: read av(m0-3)+bv(n0-3), stage A of t+3, 16 MFMA ========
    short8 av[4], bv[4];
#pragma unroll
    for (int m = 0; m < 4; m++) {
      int rw = wm * 128 + m * 16 + lr;
      av[m] = *(const short8*)&Ap[rw * 32 + sl8];
    }
#pragma unroll
    for (int n = 0; n < 4; n++) {
      int cl = wn * 64 + n * 16 + lr;
      bv[n] = *(const short8*)&Bp[cl * 32 + sl8];
    }
    if (t + 3 < NK) STG_A(t + 3);
    __builtin_amdgcn_s_barrier();
    asm volatile("s_waitcnt lgkmcnt(0)" ::: "memory");
    __builtin_amdgcn_sched_barrier(0);
    __builtin_amdgcn_s_setprio(1);
#pragma unroll
    for (int n = 0; n < 4; n++)
#pragma unroll
      for (int m = 0; m < 4; m++)
        acc[m][n] = __builtin_amdgcn_mfma_f32_16x16x32_bf16(av[m], bv[n], acc[m][n], 0, 0, 0);
    __builtin_amdgcn_s_setprio(0);
    __builtin_amdgcn_s_barrier();

    // ======== phase 1: read av(m4-7), stage B of t+3, 16 MFMA, gate t+1, publish ====
    short8 av2[4];
#pragma unroll
    for (int m = 0; m < 4; m++) {
      int rw = wm * 128 + (m + 4) * 16 + lr;
      av2[m] = *(const short8*)&Ap[rw * 32 + sl8];
    }
    if (t + 3 < NK) STG_B(t + 3);
    __builtin_amdgcn_s_barrier();
    asm volatile("s_waitcnt lgkmcnt(0)" ::: "memory");
    __builtin_amdgcn_sched_barrier(0);
    __builtin_amdgcn_s_setprio(1);
#pragma unroll
    for (int n = 0; n < 4; n++)
#pragma unroll
      for (int m = 0; m < 4; m++)
        acc[m + 4][n] = __builtin_amdgcn_mfma_f32_16x16x32_bf16(av2[m], bv[n], acc[m + 4][n], 0, 0, 0);
    __builtin_amdgcn_s_setprio(0);
    // gate tile t+1's 4 loads BEFORE the trailing barrier (publishes all waves' gates)
    if (t < NK - 3)       asm volatile("s_waitcnt vmcnt(8)" ::: "memory");
    else if (t == NK - 3) asm volatile("s_waitcnt vmcnt(4)" ::: "memory");
    else if (t == NK - 2) asm volatile("s_waitcnt vmcnt(0)" ::: "memory");
    __builtin_amdgcn_s_barrier();
  }

  // epilogue
  float bv4[4];
#pragma unroll
  for (int n = 0; n < 4; n++)
    bv4[n] = bias[(size_t)g * NOUT + ncol0 + wn * 64 + n * 16 + lr];

  if (!IS2) {
#pragma unroll
    for (int m = 0; m < 8; m++)
#pragma unroll
      for (int r4 = 0; r4 < 4; r4++) {
        int lrow = wm * 128 + m * 16 + lq * 4 + r4;
        if (lrow < valid) {
          size_t base = (size_t)(row0 + lrow) * H_DIM + ncol0 + wn * 64 + lr;
#pragma unroll
          for (int n = 0; n < 4; n++) {
            float v = acc[m][n][r4] + bv4[n];
            v = v / (1.0f + fabsf(v));
            hout[base + n * 16] = f2bf(v);
          }
        }
      }
  } else {
#pragma unroll
    for (int m = 0; m < 8; m++)
#pragma unroll
      for (int r4 = 0; r4 < 4; r4++) {
        int lrow = wm * 128 + m * 16 + lq * 4 + r4;
        if (lrow < valid) {
          int orow = rowmap[row0 + lrow];
          size_t base = (size_t)orow * P_CH + ncol0 + wn * 64 + lr;
#pragma unroll
          for (int n = 0; n < 4; n++)
            out[base + n * 16] = acc[m][n][r4] + bv4[n];
        }
      }
  }
}

extern "C" void kernel_launch(void* const* d_in, const int* in_sizes, int n_in,
                              void* d_out, int out_size, void* d_ws, size_t ws_size,
                              hipStream_t stream) {
  const float* x  = (const float*)d_in[0];
  const int* eid  = (const int*)d_in[1];
  const float* W1 = (const float*)d_in[2];
  const float* b1 = (const float*)d_in[3];
  const float* W2 = (const float*)d_in[4];
  const float* b2 = (const float*)d_in[5];
  float* out = (float*)d_out;

  unsigned short* W1t = (unsigned short*)d_ws;                       // [10][1024][512] bf16
  unsigned short* W2t = W1t + (size_t)G_SESS * H_DIM * N_UNITS;      // [10][512][1024] bf16
  unsigned short* h   = W2t + (size_t)G_SESS * P_CH * H_DIM;         // [25600][1024] bf16 (compact)
  int* rowmap    = (int*)(h + (size_t)TOT_ROWS * H_DIM);             // [25600]
  int* tile_meta = rowmap + TOT_ROWS;                                // [110][3]
  unsigned short* xb = (unsigned short*)d_out;                       // [256][100][512] bf16 (dead before gemm2 writes)

  planner<<<1, 256, 0, stream>>>(eid, rowmap, tile_meta);
  cast_x<<<2048, 256, 0, stream>>>(x, xb, B_TRIALS * F_BINS * N_UNITS / 8);
  cast_transpose<<<dim3(H_DIM / 32, N_UNITS / 32, G_SESS), 256, 0, stream>>>(W1, W1t, N_UNITS, H_DIM);
  cast_transpose<<<dim3(P_CH / 32, H_DIM / 32, G_SESS), 256, 0, stream>>>(W2, W2t, H_DIM, P_CH);
  gemm_grouped<N_UNITS, H_DIM, false><<<dim3(NT_MAX, 4), 512, 0, stream>>>(
      xb, W1t, b1, rowmap, tile_meta, h, out);
  gemm_grouped<H_DIM, P_CH, true><<<dim3(NT_MAX, 2), 512, 0, stream>>>(
      h, W2t, b2, rowmap, tile_meta, h, out);
}

// Round 7
// 140.311 us; speedup vs baseline: 1.1427x; 1.1427x over previous
//
#include <hip/hip_runtime.h>
#include <hip/hip_bf16.h>
#include <cstdint>

typedef __attribute__((ext_vector_type(8))) short short8;
typedef __attribute__((ext_vector_type(8))) unsigned short ushort8;
typedef __attribute__((ext_vector_type(4))) float f32x4;

#define B_TRIALS 256
#define F_BINS   100
#define N_UNITS  512
#define P_CH     512
#define G_SESS   10
#define H_DIM    1024  // 2N
#define TOT_ROWS (B_TRIALS * F_BINS)  // 25600
#define NT_PAD   216                  // 128-row tiles, padded to multiple of 8 (XCD chunks)

// f32 -> bf16 round-to-nearest-even (finite inputs)
__device__ __forceinline__ unsigned short f2bf(float f) {
  unsigned int u = __builtin_bit_cast(unsigned int, f);
  u += 0x7fffu + ((u >> 16) & 1u);
  return (unsigned short)(u >> 16);
}

// async global->LDS, 16B per lane; lds dest must be wave-uniform base (+lane*16 by HW)
__device__ __forceinline__ void gload16(const void* gsrc, void* ldst) {
  __builtin_amdgcn_global_load_lds(
      (const __attribute__((address_space(1))) unsigned int*)gsrc,
      (__attribute__((address_space(3))) unsigned int*)ldst, 16, 0, 0);
}

// ---------------- planner: stable counting sort of trials by eid, 128-row tiles ----------------
__global__ void planner(const int* __restrict__ eid, int* __restrict__ rowmap,
                        int* __restrict__ tile_meta) {
  __shared__ int e[B_TRIALS], cnt[G_SESS], off[G_SESS], groff[G_SESS + 1], perm[B_TRIALS];
  int t = threadIdx.x;
  e[t] = eid[t];
  if (t < G_SESS) cnt[t] = 0;
  __syncthreads();
  atomicAdd(&cnt[e[t]], 1);
  __syncthreads();
  if (t == 0) {
    int s = 0, r = 0;
    for (int g = 0; g < G_SESS; g++) {
      off[g] = s; s += cnt[g];
      groff[g] = r; r += cnt[g] * F_BINS;
    }
    groff[G_SESS] = r;  // 25600
  }
  __syncthreads();
  int g = e[t], rank = 0;
  for (int j = 0; j < t; j++) rank += (e[j] == g);
  perm[off[g] + rank] = t;
  __syncthreads();
  for (int i = t; i < TOT_ROWS; i += 256) {
    int gg = 0;
    while (gg + 1 < G_SESS && i >= groff[gg + 1]) gg++;
    int loc = i - groff[gg];
    rowmap[i] = perm[off[gg] + loc / F_BINS] * F_BINS + loc % F_BINS;
  }
  if (t == 0) {
    int ti = 0;
    for (int g2 = 0; g2 < G_SESS; g2++) {
      int rows = cnt[g2] * F_BINS;
      int base = groff[g2];
      for (int r0 = 0; r0 < rows; r0 += 128) {
        tile_meta[ti * 3 + 0] = g2;
        tile_meta[ti * 3 + 1] = base + r0;
        tile_meta[ti * 3 + 2] = (rows - r0 < 128) ? (rows - r0) : 128;
        ti++;
      }
    }
    for (; ti < NT_PAD; ti++) {
      tile_meta[ti * 3 + 0] = -1; tile_meta[ti * 3 + 1] = 0; tile_meta[ti * 3 + 2] = 0;
    }
  }
}

// ---------------- one-time casts ----------------
__global__ void cast_x(const float* __restrict__ src,
                       unsigned short* __restrict__ dst, int n8) {
  int i = blockIdx.x * blockDim.x + threadIdx.x;
  int stride = gridDim.x * blockDim.x;
  for (; i < n8; i += stride) {
    float4 v0 = ((const float4*)src)[(size_t)i * 2];
    float4 v1 = ((const float4*)src)[(size_t)i * 2 + 1];
    ushort8 w;
    w[0] = f2bf(v0.x); w[1] = f2bf(v0.y); w[2] = f2bf(v0.z); w[3] = f2bf(v0.w);
    w[4] = f2bf(v1.x); w[5] = f2bf(v1.y); w[6] = f2bf(v1.z); w[7] = f2bf(v1.w);
    ((ushort8*)dst)[i] = w;
  }
}

// src: [g][K][N] f32 -> dst: [g][N][K] bf16
__global__ void cast_transpose(const float* __restrict__ src,
                               unsigned short* __restrict__ dst,
                               int K, int N) {
  __shared__ float tile[32][33];
  int g = blockIdx.z;
  int n0 = blockIdx.x * 32, k0 = blockIdx.y * 32;
  const float* s = src + (size_t)g * K * N;
  unsigned short* d = dst + (size_t)g * N * K;
  int t = threadIdx.x;
  int r = t >> 3, c = (t & 7) * 4;
  float4 v = *(const float4*)(s + (size_t)(k0 + r) * N + n0 + c);
  tile[r][c + 0] = v.x; tile[r][c + 1] = v.y;
  tile[r][c + 2] = v.z; tile[r][c + 3] = v.w;
  __syncthreads();
  ushort4 o;
  o.x = f2bf(tile[c + 0][r]);
  o.y = f2bf(tile[c + 1][r]);
  o.z = f2bf(tile[c + 2][r]);
  o.w = f2bf(tile[c + 3][r]);
  *(ushort4*)(d + (size_t)(n0 + r) * K + k0 + c) = o;
}

// ---------------- grouped 128x256 GEMM, BK=64, single-buffer (R2 structure) ----------------
// 256 threads / 4 waves (2x2), LDS 48 KiB -> 2-3 blocks/CU. Per K-tile:
// {syncthreads | stage 12 gload16 | vmcnt(0)+lgkmcnt(0)+syncthreads | 64 MFMA}.
// XCD-chunked mapping: xcd = wg&7; within-XCD nc-fastest -> A-panel's NC blocks run
// consecutively on the SAME XCD (A L2-hit), same-(g,nc) W-panel recurs every NC slots.

template<int KTOT, int NOUT, int NC, bool IS2>
__global__ __launch_bounds__(256, 2) void gemm_grouped(
    const unsigned short* __restrict__ Asrc,
    const unsigned short* __restrict__ Wt,
    const float* __restrict__ bias,
    const int* __restrict__ rowmap,
    const int* __restrict__ tile_meta,
    unsigned short* __restrict__ hout,
    float* __restrict__ out) {
  __shared__ __align__(16) unsigned short Ash[128 * 64];  // 16 KiB
  __shared__ __align__(16) unsigned short Bsh[256 * 64];  // 32 KiB

  // bijective XCD-chunked remap
  const int wg = blockIdx.x;               // 0 .. NT_PAD*NC-1
  const int xcd = wg & 7, slot = wg >> 3;  // per-XCD slots: NT_PAD/8*NC
  const int mt = xcd * (NT_PAD / 8) + slot / NC;
  const int nc = slot % NC;

  const int g = tile_meta[mt * 3 + 0];
  if (g < 0) return;
  const int row0 = tile_meta[mt * 3 + 1];
  const int valid = tile_meta[mt * 3 + 2];
  const int ncol0 = nc * 256;

  const int tid = threadIdx.x;
  const int lane = tid & 63;
  const int w = tid >> 6;
  const int wm = w >> 1, wn = w & 1;        // 2x2 wave grid: wave owns 64 x 128
  const int lr = lane & 15, lq = lane >> 4;

  // staging sources (fixed over K; advance by 64 elems per tile).
  // chunk c = it*256 + tid: row = c>>3 = it*32 + (tid>>3), slot q = tid&7,
  // source pre-swizzle ks = q ^ (row&7) matches the read swizzle.
  const unsigned short* Wg = Wt + (size_t)g * NOUT * KTOT + (size_t)ncol0 * KTOT;
  const unsigned short* aptr[4];
  const unsigned short* bptr[8];
  {
    int rbase = tid >> 3, q = tid & 7;
#pragma unroll
    for (int it = 0; it < 4; it++) {
      int row = it * 32 + rbase;
      int ks = (q ^ (row & 7)) * 8;
      int grow = row0 + row; if (grow > TOT_ROWS - 1) grow = TOT_ROWS - 1;
      int sr = IS2 ? grow : rowmap[grow];
      aptr[it] = Asrc + (size_t)sr * KTOT + ks;
    }
#pragma unroll
    for (int it = 0; it < 8; it++) {
      int col = it * 32 + rbase;
      int ks = (q ^ (col & 7)) * 8;
      bptr[it] = Wg + (size_t)col * KTOT + ks;
    }
  }

  f32x4 acc[4][8];
#pragma unroll
  for (int m = 0; m < 4; m++)
#pragma unroll
    for (int n = 0; n < 8; n++) acc[m][n] = (f32x4){0.f, 0.f, 0.f, 0.f};

  constexpr int NK = KTOT / 64;
  for (int kt = 0; kt < NK; ++kt) {
    const size_t ko = (size_t)kt * 64;
    __syncthreads();  // previous tile's reads complete before overwrite
#pragma unroll
    for (int it = 0; it < 4; it++)
      gload16(aptr[it] + ko, &Ash[(it * 256 + (tid & 192)) * 8]);
#pragma unroll
    for (int it = 0; it < 8; it++)
      gload16(bptr[it] + ko, &Bsh[(it * 256 + (tid & 192)) * 8]);
    asm volatile("s_waitcnt vmcnt(0) lgkmcnt(0)" ::: "memory");
    __syncthreads();

#pragma unroll
    for (int kk = 0; kk < 2; kk++) {
      int kslot = kk * 4 + lq;
      short8 av[4], bv[4];
#pragma unroll
      for (int m = 0; m < 4; m++) {
        int row = wm * 64 + m * 16 + lr;
        av[m] = *(const short8*)&Ash[row * 64 + ((kslot ^ (row & 7)) * 8)];
      }
#pragma unroll
      for (int n = 0; n < 4; n++) {
        int col = wn * 128 + n * 16 + lr;
        bv[n] = *(const short8*)&Bsh[col * 64 + ((kslot ^ (col & 7)) * 8)];
      }
#pragma unroll
      for (int n = 0; n < 4; n++)
#pragma unroll
        for (int m = 0; m < 4; m++)
          acc[m][n] = __builtin_amdgcn_mfma_f32_16x16x32_bf16(av[m], bv[n], acc[m][n], 0, 0, 0);
      // second half of B columns (keeps live bv at 4 frags)
#pragma unroll
      for (int n = 0; n < 4; n++) {
        int col = wn * 128 + (n + 4) * 16 + lr;
        bv[n] = *(const short8*)&Bsh[col * 64 + ((kslot ^ (col & 7)) * 8)];
      }
#pragma unroll
      for (int n = 0; n < 4; n++)
#pragma unroll
        for (int m = 0; m < 4; m++)
          acc[m][n + 4] = __builtin_amdgcn_mfma_f32_16x16x32_bf16(av[m], bv[n], acc[m][n + 4], 0, 0, 0);
    }
  }

  // epilogue
  float bv8[8];
#pragma unroll
  for (int n = 0; n < 8; n++)
    bv8[n] = bias[(size_t)g * NOUT + ncol0 + wn * 128 + n * 16 + lr];

  if (!IS2) {
#pragma unroll
    for (int m = 0; m < 4; m++)
#pragma unroll
      for (int r4 = 0; r4 < 4; r4++) {
        int lrow = wm * 64 + m * 16 + lq * 4 + r4;
        if (lrow < valid) {
          size_t base = (size_t)(row0 + lrow) * H_DIM + ncol0 + wn * 128 + lr;
#pragma unroll
          for (int n = 0; n < 8; n++) {
            float v = acc[m][n][r4] + bv8[n];
            v = v / (1.0f + fabsf(v));
            hout[base + n * 16] = f2bf(v);
          }
        }
      }
  } else {
#pragma unroll
    for (int m = 0; m < 4; m++)
#pragma unroll
      for (int r4 = 0; r4 < 4; r4++) {
        int lrow = wm * 64 + m * 16 + lq * 4 + r4;
        if (lrow < valid) {
          int orow = rowmap[row0 + lrow];
          size_t base = (size_t)orow * P_CH + ncol0 + wn * 128 + lr;
#pragma unroll
          for (int n = 0; n < 8; n++)
            out[base + n * 16] = acc[m][n][r4] + bv8[n];
        }
      }
  }
}

extern "C" void kernel_launch(void* const* d_in, const int* in_sizes, int n_in,
                              void* d_out, int out_size, void* d_ws, size_t ws_size,
                              hipStream_t stream) {
  const float* x  = (const float*)d_in[0];
  const int* eid  = (const int*)d_in[1];
  const float* W1 = (const float*)d_in[2];
  const float* b1 = (const float*)d_in[3];
  const float* W2 = (const float*)d_in[4];
  const float* b2 = (const float*)d_in[5];
  float* out = (float*)d_out;

  unsigned short* W1t = (unsigned short*)d_ws;                       // [10][1024][512] bf16
  unsigned short* W2t = W1t + (size_t)G_SESS * H_DIM * N_UNITS;      // [10][512][1024] bf16
  unsigned short* h   = W2t + (size_t)G_SESS * P_CH * H_DIM;         // [25600][1024] bf16 (compact)
  int* rowmap    = (int*)(h + (size_t)TOT_ROWS * H_DIM);             // [25600]
  int* tile_meta = rowmap + TOT_ROWS;                                // [216][3]
  unsigned short* xb = (unsigned short*)d_out;                       // [256][100][512] bf16 (dead before gemm2 writes)

  planner<<<1, 256, 0, stream>>>(eid, rowmap, tile_meta);
  cast_x<<<2048, 256, 0, stream>>>(x, xb, B_TRIALS * F_BINS * N_UNITS / 8);
  cast_transpose<<<dim3(H_DIM / 32, N_UNITS / 32, G_SESS), 256, 0, stream>>>(W1, W1t, N_UNITS, H_DIM);
  cast_transpose<<<dim3(P_CH / 32, H_DIM / 32, G_SESS), 256, 0, stream>>>(W2, W2t, H_DIM, P_CH);
  gemm_grouped<N_UNITS, H_DIM, 4, false><<<NT_PAD * 4, 256, 0, stream>>>(
      xb, W1t, b1, rowmap, tile_meta, h, out);
  gemm_grouped<H_DIM, P_CH, 2, true><<<NT_PAD * 2, 256, 0, stream>>>(
      h, W2t, b2, rowmap, tile_meta, h, out);
}

// Round 8
// 130.394 us; speedup vs baseline: 1.2296x; 1.0761x over previous
//
#include <hip/hip_runtime.h>
#include <hip/hip_bf16.h>
#include <cstdint>

typedef __attribute__((ext_vector_type(8))) short short8;
typedef __attribute__((ext_vector_type(8))) unsigned short ushort8;
typedef __attribute__((ext_vector_type(4))) float f32x4;

#define B_TRIALS 256
#define F_BINS   100
#define N_UNITS  512
#define P_CH     512
#define G_SESS   10
#define H_DIM    1024  // 2N
#define TOT_ROWS (B_TRIALS * F_BINS)  // 25600
#define NT_PAD   216                  // 128-row tiles padded; 216 = 27 per XCD

// prep kernel block ranges
#define PREP_CASTX_BLOCKS 2048
#define PREP_W1_BLOCKS    5120   // (1024/32) x (512/32) x 10
#define PREP_W2_BLOCKS    5120   // (512/32) x (1024/32) x 10
#define PREP_TOTAL (1 + PREP_CASTX_BLOCKS + PREP_W1_BLOCKS + PREP_W2_BLOCKS)

// f32 -> bf16 round-to-nearest-even (finite inputs)
__device__ __forceinline__ unsigned short f2bf(float f) {
  unsigned int u = __builtin_bit_cast(unsigned int, f);
  u += 0x7fffu + ((u >> 16) & 1u);
  return (unsigned short)(u >> 16);
}

// async global->LDS, 16B per lane; lds dest must be wave-uniform base (+lane*16 by HW)
__device__ __forceinline__ void gload16(const void* gsrc, void* ldst) {
  __builtin_amdgcn_global_load_lds(
      (const __attribute__((address_space(1))) unsigned int*)gsrc,
      (__attribute__((address_space(3))) unsigned int*)ldst, 16, 0, 0);
}

__device__ __forceinline__ void transpose_tile(const float* __restrict__ src,
                                               unsigned short* __restrict__ dst,
                                               int K, int N, int g, int n0, int k0,
                                               float (*tile)[33]) {
  const float* s = src + (size_t)g * K * N;
  unsigned short* d = dst + (size_t)g * N * K;
  int t = threadIdx.x;
  int r = t >> 3, c = (t & 7) * 4;
  float4 v = *(const float4*)(s + (size_t)(k0 + r) * N + n0 + c);
  tile[r][c + 0] = v.x; tile[r][c + 1] = v.y;
  tile[r][c + 2] = v.z; tile[r][c + 3] = v.w;
  __syncthreads();
  ushort4 o;
  o.x = f2bf(tile[c + 0][r]);
  o.y = f2bf(tile[c + 1][r]);
  o.z = f2bf(tile[c + 2][r]);
  o.w = f2bf(tile[c + 3][r]);
  *(ushort4*)(d + (size_t)(n0 + r) * K + k0 + c) = o;
}

// ---------------- fused prep: planner | cast_x | W1 transpose | W2 transpose ----------------
__global__ void prep(const float* __restrict__ x, const int* __restrict__ eid,
                     const float* __restrict__ W1, const float* __restrict__ W2,
                     unsigned short* __restrict__ xb,
                     unsigned short* __restrict__ W1t,
                     unsigned short* __restrict__ W2t,
                     int* __restrict__ rowmap, int* __restrict__ tile_meta) {
  __shared__ float tile[32][33];
  __shared__ int e[B_TRIALS], cnt[G_SESS], off[G_SESS], groff[G_SESS + 1], perm[B_TRIALS];
  const int bid = blockIdx.x;
  const int t = threadIdx.x;

  if (bid == 0) {
    // planner: stable counting sort of trials by eid, 128-row tiles
    e[t] = eid[t];
    if (t < G_SESS) cnt[t] = 0;
    __syncthreads();
    atomicAdd(&cnt[e[t]], 1);
    __syncthreads();
    if (t == 0) {
      int s = 0, r = 0;
      for (int g = 0; g < G_SESS; g++) {
        off[g] = s; s += cnt[g];
        groff[g] = r; r += cnt[g] * F_BINS;
      }
      groff[G_SESS] = r;
    }
    __syncthreads();
    int g = e[t], rank = 0;
    for (int j = 0; j < t; j++) rank += (e[j] == g);
    perm[off[g] + rank] = t;
    __syncthreads();
    for (int i = t; i < TOT_ROWS; i += 256) {
      int gg = 0;
      while (gg + 1 < G_SESS && i >= groff[gg + 1]) gg++;
      int loc = i - groff[gg];
      rowmap[i] = perm[off[gg] + loc / F_BINS] * F_BINS + loc % F_BINS;
    }
    if (t == 0) {
      int ti = 0;
      for (int g2 = 0; g2 < G_SESS; g2++) {
        int rows = cnt[g2] * F_BINS;
        int base = groff[g2];
        for (int r0 = 0; r0 < rows; r0 += 128) {
          tile_meta[ti * 3 + 0] = g2;
          tile_meta[ti * 3 + 1] = base + r0;
          tile_meta[ti * 3 + 2] = (rows - r0 < 128) ? (rows - r0) : 128;
          ti++;
        }
      }
      for (; ti < NT_PAD; ti++) {
        tile_meta[ti * 3 + 0] = -1; tile_meta[ti * 3 + 1] = 0; tile_meta[ti * 3 + 2] = 0;
      }
    }
  } else if (bid <= PREP_CASTX_BLOCKS) {
    // cast_x: f32 -> bf16, 8 elems/thread/iter, grid-stride
    const int n8 = B_TRIALS * F_BINS * N_UNITS / 8;
    int i = (bid - 1) * 256 + t;
    const int stride = PREP_CASTX_BLOCKS * 256;
    for (; i < n8; i += stride) {
      float4 v0 = ((const float4*)x)[(size_t)i * 2];
      float4 v1 = ((const float4*)x)[(size_t)i * 2 + 1];
      ushort8 w;
      w[0] = f2bf(v0.x); w[1] = f2bf(v0.y); w[2] = f2bf(v0.z); w[3] = f2bf(v0.w);
      w[4] = f2bf(v1.x); w[5] = f2bf(v1.y); w[6] = f2bf(v1.z); w[7] = f2bf(v1.w);
      ((ushort8*)xb)[i] = w;
    }
  } else if (bid <= PREP_CASTX_BLOCKS + PREP_W1_BLOCKS) {
    // W1 [g][512][1024] -> W1t [g][1024][512]
    int tt = bid - 1 - PREP_CASTX_BLOCKS;
    int n0 = (tt & 31) * 32, k0 = ((tt >> 5) & 15) * 32, g = tt >> 9;
    transpose_tile(W1, W1t, N_UNITS, H_DIM, g, n0, k0, tile);
  } else {
    // W2 [g][1024][512] -> W2t [g][512][1024]
    int tt = bid - 1 - PREP_CASTX_BLOCKS - PREP_W1_BLOCKS;
    int n0 = (tt & 15) * 32, k0 = ((tt >> 4) & 31) * 32, g = tt >> 9;
    transpose_tile(W2, W2t, H_DIM, P_CH, g, n0, k0, tile);
  }
}

// ---------------- grouped 128x128 GEMM, BK=64, double-buffer, issue-early staging ----------------
// 256 threads / 4 waves (2x2, wave 64x64), LDS 64 KiB -> 2 blocks/CU.
// Loop: STAGE(t+1 -> buf^1) issued BEFORE compute(buf); trailing __syncthreads()
// (vmcnt(0)+lgkmcnt(0)+barrier) drains AFTER ds_read+MFMA covered the latency.
// XCD-chunked grid: xcd = wg&7, nc fastest within XCD -> A-panel and W-panels L2-resident.

template<int KTOT, int NOUT, int NC, bool IS2>
__global__ __launch_bounds__(256, 2) void gemm_grouped(
    const unsigned short* __restrict__ Asrc,
    const unsigned short* __restrict__ Wt,
    const float* __restrict__ bias,
    const int* __restrict__ rowmap,
    const int* __restrict__ tile_meta,
    unsigned short* __restrict__ hout,
    float* __restrict__ out) {
  __shared__ __align__(16) unsigned short Ash[2][128 * 64];  // 2 x 16 KiB
  __shared__ __align__(16) unsigned short Bsh[2][128 * 64];  // 2 x 16 KiB

  // bijective XCD-chunked remap (grid = NT_PAD * NC, NT_PAD % 8 == 0)
  const int wg = blockIdx.x;
  const int xcd = wg & 7, slot = wg >> 3;
  const int mt = xcd * (NT_PAD / 8) + slot / NC;
  const int nc = slot % NC;

  const int g = tile_meta[mt * 3 + 0];
  if (g < 0) return;
  const int row0 = tile_meta[mt * 3 + 1];
  const int valid = tile_meta[mt * 3 + 2];
  const int ncol0 = nc * 128;

  const int tid = threadIdx.x;
  const int lane = tid & 63;
  const int w = tid >> 6;
  const int wm = w >> 1, wn = w & 1;        // 2x2 wave grid; wave owns 64x64
  const int lr = lane & 15, lq = lane >> 4;

  // staging sources (fixed over K; +64 elems per K-tile)
  // chunk c = it*256 + tid: row = it*32 + (tid>>3), q = tid&7, ks = q ^ (row&7)
  const unsigned short* Wg = Wt + (size_t)g * NOUT * KTOT + (size_t)ncol0 * KTOT;
  const unsigned short* aptr[4];
  const unsigned short* bptr[4];
  {
    int rbase = tid >> 3, q = tid & 7;
#pragma unroll
    for (int it = 0; it < 4; it++) {
      int row = it * 32 + rbase;
      int ks = (q ^ (row & 7)) * 8;
      int grow = row0 + row; if (grow > TOT_ROWS - 1) grow = TOT_ROWS - 1;
      int sr = IS2 ? grow : rowmap[grow];
      aptr[it] = Asrc + (size_t)sr * KTOT + ks;
      bptr[it] = Wg + (size_t)row * KTOT + ks;
    }
  }

#define STAGE(kt, buf) do {                                                  \
    size_t _ko = (size_t)(kt) * 64;                                          \
    _Pragma("unroll")                                                        \
    for (int _it = 0; _it < 4; _it++) {                                      \
      gload16(aptr[_it] + _ko, &Ash[buf][(_it * 256 + (tid & 192)) * 8]);    \
      gload16(bptr[_it] + _ko, &Bsh[buf][(_it * 256 + (tid & 192)) * 8]);    \
    }                                                                        \
  } while (0)

  f32x4 acc[4][4];
#pragma unroll
  for (int m = 0; m < 4; m++)
#pragma unroll
    for (int n = 0; n < 4; n++) acc[m][n] = (f32x4){0.f, 0.f, 0.f, 0.f};

  constexpr int NK = KTOT / 64;

  STAGE(0, 0);
  __syncthreads();

  for (int t = 0; t < NK; ++t) {
    const int cur = t & 1;
    if (t + 1 < NK) STAGE(t + 1, cur ^ 1);  // issue-early: latency hides under compute

    const unsigned short* Ap = &Ash[cur][0];
    const unsigned short* Bp = &Bsh[cur][0];
    __builtin_amdgcn_s_setprio(1);
#pragma unroll
    for (int kk = 0; kk < 2; kk++) {
      int kslot = kk * 4 + lq;
      short8 av[4], bv[4];
#pragma unroll
      for (int m = 0; m < 4; m++) {
        int row = wm * 64 + m * 16 + lr;
        av[m] = *(const short8*)&Ap[row * 64 + ((kslot ^ (row & 7)) * 8)];
      }
#pragma unroll
      for (int n = 0; n < 4; n++) {
        int col = wn * 64 + n * 16 + lr;
        bv[n] = *(const short8*)&Bp[col * 64 + ((kslot ^ (col & 7)) * 8)];
      }
#pragma unroll
      for (int n = 0; n < 4; n++)
#pragma unroll
        for (int m = 0; m < 4; m++)
          acc[m][n] = __builtin_amdgcn_mfma_f32_16x16x32_bf16(av[m], bv[n], acc[m][n], 0, 0, 0);
    }
    __builtin_amdgcn_s_setprio(0);
    __syncthreads();  // drains vmcnt(0)+lgkmcnt(0) then barrier: tile t+1 published
  }

  // epilogue
  float bv4[4];
#pragma unroll
  for (int n = 0; n < 4; n++)
    bv4[n] = bias[(size_t)g * NOUT + ncol0 + wn * 64 + n * 16 + lr];

  if (!IS2) {
#pragma unroll
    for (int m = 0; m < 4; m++)
#pragma unroll
      for (int r4 = 0; r4 < 4; r4++) {
        int lrow = wm * 64 + m * 16 + lq * 4 + r4;
        if (lrow < valid) {
          size_t base = (size_t)(row0 + lrow) * H_DIM + ncol0 + wn * 64 + lr;
#pragma unroll
          for (int n = 0; n < 4; n++) {
            float v = acc[m][n][r4] + bv4[n];
            v = v / (1.0f + fabsf(v));
            hout[base + n * 16] = f2bf(v);
          }
        }
      }
  } else {
#pragma unroll
    for (int m = 0; m < 4; m++)
#pragma unroll
      for (int r4 = 0; r4 < 4; r4++) {
        int lrow = wm * 64 + m * 16 + lq * 4 + r4;
        if (lrow < valid) {
          int orow = rowmap[row0 + lrow];
          size_t base = (size_t)orow * P_CH + ncol0 + wn * 64 + lr;
#pragma unroll
          for (int n = 0; n < 4; n++)
            out[base + n * 16] = acc[m][n][r4] + bv4[n];
        }
      }
  }
#undef STAGE
}

extern "C" void kernel_launch(void* const* d_in, const int* in_sizes, int n_in,
                              void* d_out, int out_size, void* d_ws, size_t ws_size,
                              hipStream_t stream) {
  const float* x  = (const float*)d_in[0];
  const int* eid  = (const int*)d_in[1];
  const float* W1 = (const float*)d_in[2];
  const float* b1 = (const float*)d_in[3];
  const float* W2 = (const float*)d_in[4];
  const float* b2 = (const float*)d_in[5];
  float* out = (float*)d_out;

  unsigned short* W1t = (unsigned short*)d_ws;                       // [10][1024][512] bf16
  unsigned short* W2t = W1t + (size_t)G_SESS * H_DIM * N_UNITS;      // [10][512][1024] bf16
  unsigned short* h   = W2t + (size_t)G_SESS * P_CH * H_DIM;         // [25600][1024] bf16 (compact)
  int* rowmap    = (int*)(h + (size_t)TOT_ROWS * H_DIM);             // [25600]
  int* tile_meta = rowmap + TOT_ROWS;                                // [216][3]
  unsigned short* xb = (unsigned short*)d_out;                       // [256][100][512] bf16 (dead before gemm2 writes)

  prep<<<PREP_TOTAL, 256, 0, stream>>>(x, eid, W1, W2, xb, W1t, W2t, rowmap, tile_meta);
  gemm_grouped<N_UNITS, H_DIM, 8, false><<<NT_PAD * 8, 256, 0, stream>>>(
      xb, W1t, b1, rowmap, tile_meta, h, out);
  gemm_grouped<H_DIM, P_CH, 4, true><<<NT_PAD * 4, 256, 0, stream>>>(
      h, W2t, b2, rowmap, tile_meta, h, out);
}

// Round 9
// 116.205 us; speedup vs baseline: 1.3797x; 1.1221x over previous
//
#include <hip/hip_runtime.h>
#include <hip/hip_bf16.h>
#include <cstdint>

typedef __attribute__((ext_vector_type(8))) short short8;
typedef __attribute__((ext_vector_type(8))) unsigned short ushort8;
typedef __attribute__((ext_vector_type(4))) float f32x4;

#define B_TRIALS 256
#define F_BINS   100
#define N_UNITS  512
#define P_CH     512
#define G_SESS   10
#define H_DIM    1024  // 2N
#define TOT_ROWS (B_TRIALS * F_BINS)  // 25600
#define NT_PAD   216                  // 128-row tiles padded; 216 = 27 per XCD

// prep kernel block ranges
#define PREP_CASTX_BLOCKS 2048
#define PREP_W1_BLOCKS    5120   // (1024/32) x (512/32) x 10
#define PREP_W2_BLOCKS    5120   // (512/32) x (1024/32) x 10
#define PREP_TOTAL (1 + PREP_CASTX_BLOCKS + PREP_W1_BLOCKS + PREP_W2_BLOCKS)

// f32 -> bf16 round-to-nearest-even (finite inputs)
__device__ __forceinline__ unsigned short f2bf(float f) {
  unsigned int u = __builtin_bit_cast(unsigned int, f);
  u += 0x7fffu + ((u >> 16) & 1u);
  return (unsigned short)(u >> 16);
}

// async global->LDS, 16B per lane; lds dest must be wave-uniform base (+lane*16 by HW)
__device__ __forceinline__ void gload16(const void* gsrc, void* ldst) {
  __builtin_amdgcn_global_load_lds(
      (const __attribute__((address_space(1))) unsigned int*)gsrc,
      (__attribute__((address_space(3))) unsigned int*)ldst, 16, 0, 0);
}

__device__ __forceinline__ void transpose_tile(const float* __restrict__ src,
                                               unsigned short* __restrict__ dst,
                                               int K, int N, int g, int n0, int k0,
                                               float (*tile)[33]) {
  const float* s = src + (size_t)g * K * N;
  unsigned short* d = dst + (size_t)g * N * K;
  int t = threadIdx.x;
  int r = t >> 3, c = (t & 7) * 4;
  float4 v = *(const float4*)(s + (size_t)(k0 + r) * N + n0 + c);
  tile[r][c + 0] = v.x; tile[r][c + 1] = v.y;
  tile[r][c + 2] = v.z; tile[r][c + 3] = v.w;
  __syncthreads();
  ushort4 o;
  o.x = f2bf(tile[c + 0][r]);
  o.y = f2bf(tile[c + 1][r]);
  o.z = f2bf(tile[c + 2][r]);
  o.w = f2bf(tile[c + 3][r]);
  *(ushort4*)(d + (size_t)(n0 + r) * K + k0 + c) = o;
}

// ---------------- fused prep: planner | cast_x | W1 transpose | W2 transpose ----------------
__global__ void prep(const float* __restrict__ x, const int* __restrict__ eid,
                     const float* __restrict__ W1, const float* __restrict__ W2,
                     unsigned short* __restrict__ xb,
                     unsigned short* __restrict__ W1t,
                     unsigned short* __restrict__ W2t,
                     int* __restrict__ rowmap, int* __restrict__ tile_meta) {
  __shared__ float tile[32][33];
  __shared__ int e[B_TRIALS], cnt[G_SESS], off[G_SESS], groff[G_SESS + 1], perm[B_TRIALS];
  const int bid = blockIdx.x;
  const int t = threadIdx.x;

  if (bid == 0) {
    // planner: stable counting sort of trials by eid, 128-row tiles
    e[t] = eid[t];
    if (t < G_SESS) cnt[t] = 0;
    __syncthreads();
    atomicAdd(&cnt[e[t]], 1);
    __syncthreads();
    if (t == 0) {
      int s = 0, r = 0;
      for (int g = 0; g < G_SESS; g++) {
        off[g] = s; s += cnt[g];
        groff[g] = r; r += cnt[g] * F_BINS;
      }
      groff[G_SESS] = r;
    }
    __syncthreads();
    int g = e[t], rank = 0;
    for (int j = 0; j < t; j++) rank += (e[j] == g);
    perm[off[g] + rank] = t;
    __syncthreads();
    for (int i = t; i < TOT_ROWS; i += 256) {
      int gg = 0;
      while (gg + 1 < G_SESS && i >= groff[gg + 1]) gg++;
      int loc = i - groff[gg];
      rowmap[i] = perm[off[gg] + loc / F_BINS] * F_BINS + loc % F_BINS;
    }
    if (t == 0) {
      int ti = 0;
      for (int g2 = 0; g2 < G_SESS; g2++) {
        int rows = cnt[g2] * F_BINS;
        int base = groff[g2];
        for (int r0 = 0; r0 < rows; r0 += 128) {
          tile_meta[ti * 3 + 0] = g2;
          tile_meta[ti * 3 + 1] = base + r0;
          tile_meta[ti * 3 + 2] = (rows - r0 < 128) ? (rows - r0) : 128;
          ti++;
        }
      }
      for (; ti < NT_PAD; ti++) {
        tile_meta[ti * 3 + 0] = -1; tile_meta[ti * 3 + 1] = 0; tile_meta[ti * 3 + 2] = 0;
      }
    }
  } else if (bid <= PREP_CASTX_BLOCKS) {
    // cast_x: f32 -> bf16, 8 elems/thread/iter, grid-stride
    const int n8 = B_TRIALS * F_BINS * N_UNITS / 8;
    int i = (bid - 1) * 256 + t;
    const int stride = PREP_CASTX_BLOCKS * 256;
    for (; i < n8; i += stride) {
      float4 v0 = ((const float4*)x)[(size_t)i * 2];
      float4 v1 = ((const float4*)x)[(size_t)i * 2 + 1];
      ushort8 w;
      w[0] = f2bf(v0.x); w[1] = f2bf(v0.y); w[2] = f2bf(v0.z); w[3] = f2bf(v0.w);
      w[4] = f2bf(v1.x); w[5] = f2bf(v1.y); w[6] = f2bf(v1.z); w[7] = f2bf(v1.w);
      ((ushort8*)xb)[i] = w;
    }
  } else if (bid <= PREP_CASTX_BLOCKS + PREP_W1_BLOCKS) {
    // W1 [g][512][1024] -> W1t [g][1024][512]
    int tt = bid - 1 - PREP_CASTX_BLOCKS;
    int n0 = (tt & 31) * 32, k0 = ((tt >> 5) & 15) * 32, g = tt >> 9;
    transpose_tile(W1, W1t, N_UNITS, H_DIM, g, n0, k0, tile);
  } else {
    // W2 [g][1024][512] -> W2t [g][512][1024]
    int tt = bid - 1 - PREP_CASTX_BLOCKS - PREP_W1_BLOCKS;
    int n0 = (tt & 15) * 32, k0 = ((tt >> 4) & 31) * 32, g = tt >> 9;
    transpose_tile(W2, W2t, H_DIM, P_CH, g, n0, k0, tile);
  }
}

// ---------------- grouped 128x128 GEMM, BK=64, SINGLE-buffer 32 KiB (m97 geometry) ----------------
// 256 threads / 4 waves (2x2, wave 64x64). LDS 32 KiB + VGPR<=128 + launch_bounds(256,4)
// -> 4 blocks/CU co-resident: the barrier-drain stall of one block is covered by the
// other blocks' compute (m114 mechanism) -- no intra-block pipelining needed.
// Loop: {syncthreads | stage 8 gload16 | vmcnt(0)+lgkmcnt(0) | syncthreads | 16 ds_read + 32 MFMA}.
// XCD-chunked grid: xcd = wg&7, nc fastest within XCD -> A-panel + W-panels L2-resident.

template<int KTOT, int NOUT, int NC, bool IS2>
__global__ __launch_bounds__(256, 4) void gemm_grouped(
    const unsigned short* __restrict__ Asrc,
    const unsigned short* __restrict__ Wt,
    const float* __restrict__ bias,
    const int* __restrict__ rowmap,
    const int* __restrict__ tile_meta,
    unsigned short* __restrict__ hout,
    float* __restrict__ out) {
  __shared__ __align__(16) unsigned short Ash[128 * 64];  // 16 KiB
  __shared__ __align__(16) unsigned short Bsh[128 * 64];  // 16 KiB

  // bijective XCD-chunked remap (grid = NT_PAD * NC, NT_PAD % 8 == 0)
  const int wg = blockIdx.x;
  const int xcd = wg & 7, slot = wg >> 3;
  const int mt = xcd * (NT_PAD / 8) + slot / NC;
  const int nc = slot % NC;

  const int g = tile_meta[mt * 3 + 0];
  if (g < 0) return;
  const int row0 = tile_meta[mt * 3 + 1];
  const int valid = tile_meta[mt * 3 + 2];
  const int ncol0 = nc * 128;

  const int tid = threadIdx.x;
  const int lane = tid & 63;
  const int w = tid >> 6;
  const int wm = w >> 1, wn = w & 1;        // 2x2 wave grid; wave owns 64x64
  const int lr = lane & 15, lq = lane >> 4;

  // staging sources (fixed over K; +64 elems per K-tile)
  // chunk c = it*256 + tid: row = it*32 + (tid>>3), q = tid&7, ks = q ^ (row&7)
  const unsigned short* Wg = Wt + (size_t)g * NOUT * KTOT + (size_t)ncol0 * KTOT;
  const unsigned short* aptr[4];
  const unsigned short* bptr[4];
  {
    int rbase = tid >> 3, q = tid & 7;
#pragma unroll
    for (int it = 0; it < 4; it++) {
      int row = it * 32 + rbase;
      int ks = (q ^ (row & 7)) * 8;
      int grow = row0 + row; if (grow > TOT_ROWS - 1) grow = TOT_ROWS - 1;
      int sr = IS2 ? grow : rowmap[grow];
      aptr[it] = Asrc + (size_t)sr * KTOT + ks;
      bptr[it] = Wg + (size_t)row * KTOT + ks;
    }
  }

  f32x4 acc[4][4];
#pragma unroll
  for (int m = 0; m < 4; m++)
#pragma unroll
    for (int n = 0; n < 4; n++) acc[m][n] = (f32x4){0.f, 0.f, 0.f, 0.f};

  constexpr int NK = KTOT / 64;

  for (int t = 0; t < NK; ++t) {
    const size_t ko = (size_t)t * 64;
    __syncthreads();  // all waves' reads of previous tile complete before overwrite
#pragma unroll
    for (int it = 0; it < 4; it++) {
      gload16(aptr[it] + ko, &Ash[(it * 256 + (tid & 192)) * 8]);
      gload16(bptr[it] + ko, &Bsh[(it * 256 + (tid & 192)) * 8]);
    }
    asm volatile("s_waitcnt vmcnt(0) lgkmcnt(0)" ::: "memory");
    __syncthreads();  // publish staged tile

#pragma unroll
    for (int kk = 0; kk < 2; kk++) {
      int kslot = kk * 4 + lq;
      short8 av[4], bv[4];
#pragma unroll
      for (int m = 0; m < 4; m++) {
        int row = wm * 64 + m * 16 + lr;
        av[m] = *(const short8*)&Ash[row * 64 + ((kslot ^ (row & 7)) * 8)];
      }
#pragma unroll
      for (int n = 0; n < 4; n++) {
        int col = wn * 64 + n * 16 + lr;
        bv[n] = *(const short8*)&Bsh[col * 64 + ((kslot ^ (col & 7)) * 8)];
      }
#pragma unroll
      for (int n = 0; n < 4; n++)
#pragma unroll
        for (int m = 0; m < 4; m++)
          acc[m][n] = __builtin_amdgcn_mfma_f32_16x16x32_bf16(av[m], bv[n], acc[m][n], 0, 0, 0);
    }
  }

  // epilogue
  float bv4[4];
#pragma unroll
  for (int n = 0; n < 4; n++)
    bv4[n] = bias[(size_t)g * NOUT + ncol0 + wn * 64 + n * 16 + lr];

  if (!IS2) {
#pragma unroll
    for (int m = 0; m < 4; m++)
#pragma unroll
      for (int r4 = 0; r4 < 4; r4++) {
        int lrow = wm * 64 + m * 16 + lq * 4 + r4;
        if (lrow < valid) {
          size_t base = (size_t)(row0 + lrow) * H_DIM + ncol0 + wn * 64 + lr;
#pragma unroll
          for (int n = 0; n < 4; n++) {
            float v = acc[m][n][r4] + bv4[n];
            v = v / (1.0f + fabsf(v));
            hout[base + n * 16] = f2bf(v);
          }
        }
      }
  } else {
#pragma unroll
    for (int m = 0; m < 4; m++)
#pragma unroll
      for (int r4 = 0; r4 < 4; r4++) {
        int lrow = wm * 64 + m * 16 + lq * 4 + r4;
        if (lrow < valid) {
          int orow = rowmap[row0 + lrow];
          size_t base = (size_t)orow * P_CH + ncol0 + wn * 64 + lr;
#pragma unroll
          for (int n = 0; n < 4; n++)
            out[base + n * 16] = acc[m][n][r4] + bv4[n];
        }
      }
  }
}

extern "C" void kernel_launch(void* const* d_in, const int* in_sizes, int n_in,
                              void* d_out, int out_size, void* d_ws, size_t ws_size,
                              hipStream_t stream) {
  const float* x  = (const float*)d_in[0];
  const int* eid  = (const int*)d_in[1];
  const float* W1 = (const float*)d_in[2];
  const float* b1 = (const float*)d_in[3];
  const float* W2 = (const float*)d_in[4];
  const float* b2 = (const float*)d_in[5];
  float* out = (float*)d_out;

  unsigned short* W1t = (unsigned short*)d_ws;                       // [10][1024][512] bf16
  unsigned short* W2t = W1t + (size_t)G_SESS * H_DIM * N_UNITS;      // [10][512][1024] bf16
  unsigned short* h   = W2t + (size_t)G_SESS * P_CH * H_DIM;         // [25600][1024] bf16 (compact)
  int* rowmap    = (int*)(h + (size_t)TOT_ROWS * H_DIM);             // [25600]
  int* tile_meta = rowmap + TOT_ROWS;                                // [216][3]
  unsigned short* xb = (unsigned short*)d_out;                       // [256][100][512] bf16 (dead before gemm2 writes)

  prep<<<PREP_TOTAL, 256, 0, stream>>>(x, eid, W1, W2, xb, W1t, W2t, rowmap, tile_meta);
  gemm_grouped<N_UNITS, H_DIM, 8, false><<<NT_PAD * 8, 256, 0, stream>>>(
      xb, W1t, b1, rowmap, tile_meta, h, out);
  gemm_grouped<H_DIM, P_CH, 4, true><<<NT_PAD * 4, 256, 0, stream>>>(
      h, W2t, b2, rowmap, tile_meta, h, out);
}